// Round 2
// baseline (355.141 us; speedup 1.0000x reference)
//
#include <hip/hip_runtime.h>

// out[n,k] = ||x[n] - w[k]||^2 = x2[n] + w2[k] - 2 * dot(x[n], w[k])
// N = 524288 rows, D = 84, K = 10 prototypes. All fp32.
// Memory-bound: ~197 MB total traffic -> ~31 us floor at 6.3 TB/s.

#define RBF_D 84
#define RBF_K 10
#define RBF_BLOCK 256

__global__ __launch_bounds__(RBF_BLOCK)
void RBFUnit_73409581023396_kernel(const float* __restrict__ x,
                                   const float* __restrict__ w,
                                   float* __restrict__ out) {
    __shared__ float w_lds[RBF_K][RBF_D];   // 3.36 KB
    __shared__ float w2_lds[RBF_K];

    const int tid = threadIdx.x;

    // Cooperative stage of the tiny weight matrix into LDS.
    for (int i = tid; i < RBF_K * RBF_D; i += RBF_BLOCK) {
        (&w_lds[0][0])[i] = w[i];
    }
    __syncthreads();

    // w2[k] = sum_d w[k][d]^2 (10 threads, trivial).
    if (tid < RBF_K) {
        float s = 0.0f;
        for (int d = 0; d < RBF_D; ++d) s = fmaf(w_lds[tid][d], w_lds[tid][d], s);
        w2_lds[tid] = s;
    }
    __syncthreads();

    const int row = blockIdx.x * RBF_BLOCK + tid;   // grid sized exactly N/256

    // Row base: row * 84 floats = row * 336 bytes -> always 16B aligned.
    const float4* __restrict__ xr =
        reinterpret_cast<const float4*>(x + (size_t)row * RBF_D);

    float dot[RBF_K];
    #pragma unroll
    for (int p = 0; p < RBF_K; ++p) dot[p] = 0.0f;
    float x2 = 0.0f;

    // 21 float4 loads per row; LDS weight reads are wave-uniform (broadcast).
    for (int c = 0; c < RBF_D / 4; ++c) {
        const float4 v = xr[c];
        const float e[4] = {v.x, v.y, v.z, v.w};
        #pragma unroll
        for (int j = 0; j < 4; ++j) {
            const float xv = e[j];
            const int d = c * 4 + j;
            x2 = fmaf(xv, xv, x2);
            #pragma unroll
            for (int p = 0; p < RBF_K; ++p) {
                dot[p] = fmaf(xv, w_lds[p][d], dot[p]);
            }
        }
    }

    float res[RBF_K];
    #pragma unroll
    for (int p = 0; p < RBF_K; ++p) {
        res[p] = x2 + w2_lds[p] - 2.0f * dot[p];
    }

    // 40B per row: 5x float2 stores (8B-aligned for every row).
    float2* __restrict__ o = reinterpret_cast<float2*>(out + (size_t)row * RBF_K);
    #pragma unroll
    for (int j = 0; j < RBF_K / 2; ++j) {
        o[j] = make_float2(res[2 * j], res[2 * j + 1]);
    }
}

extern "C" void kernel_launch(void* const* d_in, const int* in_sizes, int n_in,
                              void* d_out, int out_size, void* d_ws, size_t ws_size,
                              hipStream_t stream) {
    const float* x = (const float*)d_in[0];
    const float* w = (const float*)d_in[1];
    float* out = (float*)d_out;

    const int n_rows = in_sizes[0] / RBF_D;           // 524288
    const int grid = n_rows / RBF_BLOCK;              // 2048, exact

    RBFUnit_73409581023396_kernel<<<grid, RBF_BLOCK, 0, stream>>>(x, w, out);
}

// Round 3
// 257.667 us; speedup vs baseline: 1.3783x; 1.3783x over previous
//
#include <hip/hip_runtime.h>

// out[n,k] = ||x[n] - w[k]||^2 = x2[n] + w2[k] - 2 * dot(x[n], w[k])
// N = 524288 rows, D = 84, K = 10. fp32. Memory-bound: ~197 MB -> ~31 us floor.
//
// Round-2 counters showed 2.94x HBM over-fetch (517 MB vs 176 MB ideal): the
// 336B lane stride + compute interleaved between the 21 row loads meant lines
// were evicted from L1/L2 before their other 16B chunks were consumed.
// Fix: load the whole row into registers as one back-to-back burst of 21
// float4 loads (MSHR-coalesced -> each line fetched once), THEN compute.

#define RBF_D 84
#define RBF_K 10
#define RBF_BLOCK 256
#define RBF_F4 (RBF_D / 4)   // 21 float4 per row

__global__ __launch_bounds__(RBF_BLOCK, 4)   // cap VGPR so 4 waves/SIMD (16/CU)
void RBFUnit_73409581023396_kernel(const float* __restrict__ x,
                                   const float* __restrict__ w,
                                   float* __restrict__ out) {
    __shared__ float w_lds[RBF_K][RBF_D];   // 3.36 KB; row stride 336B = 16B-aligned
    __shared__ float w2_lds[RBF_K];

    const int tid = threadIdx.x;

    // Stage the tiny weight matrix into LDS (coalesced enough; 840 floats).
    for (int i = tid; i < RBF_K * RBF_D; i += RBF_BLOCK) {
        (&w_lds[0][0])[i] = w[i];
    }
    __syncthreads();

    if (tid < RBF_K) {
        float s = 0.0f;
        for (int d = 0; d < RBF_D; ++d) s = fmaf(w_lds[tid][d], w_lds[tid][d], s);
        w2_lds[tid] = s;
    }
    __syncthreads();

    const int row = blockIdx.x * RBF_BLOCK + tid;   // grid = N/256 exactly

    // ---- Phase 1: burst-load the full row (21 x float4, back-to-back). ----
    // Row base = row * 336 B -> 16B aligned. All 21 loads issue with no
    // intervening compute so same-line misses coalesce in MSHRs.
    const float4* __restrict__ xr =
        reinterpret_cast<const float4*>(x + (size_t)row * RBF_D);
    float4 v[RBF_F4];
    #pragma unroll
    for (int c = 0; c < RBF_F4; ++c) {
        v[c] = xr[c];
    }
    // Keep the load burst before all compute.
    __builtin_amdgcn_sched_barrier(0);

    // ---- Phase 2: compute. Weight reads are wave-uniform LDS broadcasts. ----
    float dot[RBF_K];
    #pragma unroll
    for (int p = 0; p < RBF_K; ++p) dot[p] = 0.0f;
    float x2 = 0.0f;

    #pragma unroll
    for (int c = 0; c < RBF_F4; ++c) {
        const float4 xv = v[c];
        x2 = fmaf(xv.x, xv.x, x2);
        x2 = fmaf(xv.y, xv.y, x2);
        x2 = fmaf(xv.z, xv.z, x2);
        x2 = fmaf(xv.w, xv.w, x2);
        #pragma unroll
        for (int p = 0; p < RBF_K; ++p) {
            const float4 wv =
                *reinterpret_cast<const float4*>(&w_lds[p][c * 4]);
            dot[p] = fmaf(xv.x, wv.x, dot[p]);
            dot[p] = fmaf(xv.y, wv.y, dot[p]);
            dot[p] = fmaf(xv.z, wv.z, dot[p]);
            dot[p] = fmaf(xv.w, wv.w, dot[p]);
        }
    }

    float res[RBF_K];
    #pragma unroll
    for (int p = 0; p < RBF_K; ++p) {
        res[p] = x2 + w2_lds[p] - 2.0f * dot[p];
    }

    // 40B per row as 5x float2 (always 8B-aligned). WRITE_SIZE was already
    // ideal (20.5 MB) with this pattern.
    float2* __restrict__ o = reinterpret_cast<float2*>(out + (size_t)row * RBF_K);
    #pragma unroll
    for (int j = 0; j < RBF_K / 2; ++j) {
        o[j] = make_float2(res[2 * j], res[2 * j + 1]);
    }
}

extern "C" void kernel_launch(void* const* d_in, const int* in_sizes, int n_in,
                              void* d_out, int out_size, void* d_ws, size_t ws_size,
                              hipStream_t stream) {
    const float* x = (const float*)d_in[0];
    const float* w = (const float*)d_in[1];
    float* out = (float*)d_out;

    const int n_rows = in_sizes[0] / RBF_D;           // 524288
    const int grid = n_rows / RBF_BLOCK;              // 2048, exact

    RBFUnit_73409581023396_kernel<<<grid, RBF_BLOCK, 0, stream>>>(x, w, out);
}

// Round 5
// 252.715 us; speedup vs baseline: 1.4053x; 1.0196x over previous
//
#include <hip/hip_runtime.h>

// out[n,k] = ||x[n] - w[k]||^2 = x2[n] + w2[k] - 2 * dot(x[n], w[k])
// N = 524288 rows, D = 84, K = 10. fp32. Memory floor ~31 us (197 MB @ 6.3 TB/s).
//
// Round-3 post-mortem: burst row-load fixed the 2.94x HBM over-fetch
// (kernel ~180 -> ~82 us), but compute now bottlenecks on 210 ds_read_b128
// per wave (4 FMAs per DS read) sharing one LDS pipe across 16 waves/CU
// (~34 us of DS occupancy) on top of 924 VALU instrs/wave.
// Fix: weight reads are wave-uniform -> read w straight from global with
// uniform indices so they compile to s_load_dwordx4 via the scalar K$
// (3.4 KB, fully resident). LDS pipe goes to zero; FMAs take the weight
// as their one allowed SGPR operand.

#define RBF_D 84
#define RBF_K 10
#define RBF_BLOCK 256
#define RBF_F4 (RBF_D / 4)   // 21 float4 per row

__global__ __launch_bounds__(RBF_BLOCK, 4)   // ~110 VGPR -> 4 waves/SIMD
void RBFUnit_73409581023396_kernel(const float* __restrict__ x,
                                   const float* __restrict__ w,
                                   float* __restrict__ out) {
    __shared__ float w2_lds[RBF_K];          // only 40 B of LDS now

    const int tid = threadIdx.x;

    // w2[k] = sum_d w[k][d]^2 — 10 threads, 840 cached reads, negligible.
    if (tid < RBF_K) {
        float s = 0.0f;
        for (int d = 0; d < RBF_D; ++d) {
            const float wv = w[tid * RBF_D + d];
            s = fmaf(wv, wv, s);
        }
        w2_lds[tid] = s;
    }
    __syncthreads();

    const int row = blockIdx.x * RBF_BLOCK + tid;   // grid = N/256 exactly

    // ---- Phase 1: burst-load the full row (21 x float4, back-to-back). ----
    // Row base = row * 336 B -> always 16B aligned; same-line misses coalesce
    // in MSHRs so each HBM line is fetched exactly once.
    const float4* __restrict__ xr =
        reinterpret_cast<const float4*>(x + (size_t)row * RBF_D);
    float4 v[RBF_F4];
    #pragma unroll
    for (int c = 0; c < RBF_F4; ++c) {
        v[c] = xr[c];
    }
    // Pin the load burst before all compute (and before any w s_loads).
    __builtin_amdgcn_sched_barrier(0);

    // ---- Phase 2: compute. Weight reads are wave-uniform global reads ----
    // w is 210 float4 chunks: chunk (p,c) = wq[p*21 + c], 16B-aligned.
    // Uniform index + __restrict__ => scalar s_load_dwordx4 through K$.
    const float4* __restrict__ wq = reinterpret_cast<const float4*>(w);

    float dot[RBF_K];
    #pragma unroll
    for (int p = 0; p < RBF_K; ++p) dot[p] = 0.0f;
    float x2 = 0.0f;

    #pragma unroll
    for (int c = 0; c < RBF_F4; ++c) {
        const float4 xv = v[c];
        x2 = fmaf(xv.x, xv.x, x2);
        x2 = fmaf(xv.y, xv.y, x2);
        x2 = fmaf(xv.z, xv.z, x2);
        x2 = fmaf(xv.w, xv.w, x2);
        #pragma unroll
        for (int p = 0; p < RBF_K; ++p) {
            const float4 wv = wq[p * RBF_F4 + c];   // uniform -> SGPR
            dot[p] = fmaf(xv.x, wv.x, dot[p]);
            dot[p] = fmaf(xv.y, wv.y, dot[p]);
            dot[p] = fmaf(xv.z, wv.z, dot[p]);
            dot[p] = fmaf(xv.w, wv.w, dot[p]);
        }
    }

    float res[RBF_K];
    #pragma unroll
    for (int p = 0; p < RBF_K; ++p) {
        res[p] = x2 + w2_lds[p] - 2.0f * dot[p];
    }

    // 40 B per row as 5x float2 (always 8B-aligned); WRITE_SIZE already ideal.
    float2* __restrict__ o = reinterpret_cast<float2*>(out + (size_t)row * RBF_K);
    #pragma unroll
    for (int j = 0; j < RBF_K / 2; ++j) {
        o[j] = make_float2(res[2 * j], res[2 * j + 1]);
    }
}

extern "C" void kernel_launch(void* const* d_in, const int* in_sizes, int n_in,
                              void* d_out, int out_size, void* d_ws, size_t ws_size,
                              hipStream_t stream) {
    const float* x = (const float*)d_in[0];
    const float* w = (const float*)d_in[1];
    float* out = (float*)d_out;

    const int n_rows = in_sizes[0] / RBF_D;           // 524288
    const int grid = n_rows / RBF_BLOCK;              // 2048, exact

    RBFUnit_73409581023396_kernel<<<grid, RBF_BLOCK, 0, stream>>>(x, w, out);
}